// Round 2
// baseline (417.992 us; speedup 1.0000x reference)
//
#include <hip/hip_runtime.h>

// VQBlock: x[16,64,64,256] fp32, dict[256,1024] fp32.
// out = concat(q_st flat [16777216], loss [1]) fp32.
//
// Round 4 structure:
//  - f16 MFMA fast path (16x16x32_f16) for distances, M=32 rows/wave (2 mtiles),
//    RPB=128, grid 512 (2 blocks/CU, LDS-capped).
//  - 2-phase pipeline: global_load_lds stages chunk cc+1 into LDS buf^1 while
//    computing chunk cc; ONE barrier per chunk (T3-minimum, guide §5.5).
//  - Staging source addresses pre-permuted so compute ds_read_b128 is
//    lane-contiguous (conflict-free); LDS dest stays linear (m104/m173 rule).
//  - Packed-u32 top-2 selection: pk = (bits(dn+8-2acc) & ~0x3FF) | k.
//    Trunc err <= 9.8e-4 (values in [1.8,14.6)); EPS_TIE widened 4e-3 -> 6e-3
//    keeps the previously-proven delta<=1e-3 wrong-pick margin. Ties/ambiguous
//    rows go through the UNCHANGED np-fp32-faithful rescan.
//  - q_st written as fl(x + fl(q-x)) to match np exactly.

#define NROWS   65536
#define DIM     256
#define NCODE   1024
#define RPB     128                 // rows per block = 4 waves x 32 rows
#define NBLK    (NROWS / RPB)       // 512
#define EPS_TIE 6e-3f               // 4e-3 (f16 err margin) + ~1e-3 pack trunc + slack

typedef _Float16 half8 __attribute__((ext_vector_type(8)));
typedef float    f32x4 __attribute__((ext_vector_type(4)));

// ---------- merged prep kernel ----------
// transpose + f16 MFMA-B pack + (blocks 0-3) dictnorm with +8 bias baked in.
__global__ void k_prep(const float* __restrict__ dict, float* __restrict__ dictT,
                       float* __restrict__ dictnorm, unsigned short* __restrict__ packB) {
    int gid = blockIdx.x * 256 + threadIdx.x;          // grid 256 x 256
#pragma unroll
    for (int ii = 0; ii < 4; ++ii) {
        int o = ii * 65536 + gid;
        // transpose (coalesced read)
        { int d = o >> 10, k = o & 1023; dictT[k * DIM + d] = dict[o]; }
        // pack -> packB[kk*32768 + n*32 + q*8 + j] = f16(dict[(kk*32+q*8+j)][n])
        { int j = o & 7, q = (o >> 3) & 3, n = (o >> 5) & 1023, kk = o >> 15;
          int d = kk * 32 + q * 8 + j;
          _Float16 h = (_Float16)dict[d * NCODE + n];   // RTN cvt
          packB[o] = *(unsigned short*)&h; }
    }
    if (blockIdx.x < 4) {
        int k = blockIdx.x * 256 + threadIdx.x;
        float s = 0.f;
#pragma unroll 8
        for (int d = 0; d < DIM; ++d) {
            float v = dict[d * NCODE + k];
            s = fmaf(v, v, s);
        }
        dictnorm[k] = s + 8.0f;    // bias for packed-selection positivity; cancels in gaps
    }
}

// np pairwise sum of squares of 128 contiguous elements
__device__ __forceinline__ float np_pairwise_sq_128(const float* a, int stride) {
    float r[8];
#pragma unroll
    for (int j = 0; j < 8; ++j) {
        float v = a[j * stride];
        r[j] = __fmul_rn(v, v);
    }
    for (int i = 8; i < 128; i += 8) {
#pragma unroll
        for (int j = 0; j < 8; ++j) {
            float v = a[(i + j) * stride];
            r[j] = __fadd_rn(r[j], __fmul_rn(v, v));
        }
    }
    return __fadd_rn(__fadd_rn(__fadd_rn(r[0], r[1]), __fadd_rn(r[2], r[3])),
                     __fadd_rn(__fadd_rn(r[4], r[5]), __fadd_rn(r[6], r[7])));
}

// ---------- main kernel ----------

// Stage chunk cc's 32KB of packB into bstage[buf] via global_load_lds (16B/lane).
// LDS dest is linear (base + tid*16); the SOURCE address carries the permutation
// so that compute-phase reads are lane-contiguous:
//   LDS slot s (=tid) holds packB data for (n = c0 + (s>>6)*16 + (s&15), q = (s>>4)&3).
#define STAGE(buf, cc) do {                                                            \
    const int _t = tid >> 6, _q = (tid >> 4) & 3, _n = tid & 15;                       \
    const unsigned short* _s = packB + (size_t)(cc) * 2048                             \
                             + ((_t * 16 + _n) * 32 + _q * 8);                         \
    unsigned short* _d = &bstage[buf][tid * 8];                                        \
    _Pragma("unroll")                                                                  \
    for (int _k = 0; _k < 8; ++_k)                                                     \
        __builtin_amdgcn_global_load_lds(                                              \
            (const __attribute__((address_space(1))) unsigned int*)(_s + (size_t)_k * 32768), \
            (__attribute__((address_space(3))) unsigned int*)(_d + _k * 2048),         \
            16, 0, 0);                                                                 \
} while (0)

__global__ __launch_bounds__(256, 2) void k_vq(
    const float* __restrict__ x, const float* __restrict__ dict,
    const float* __restrict__ dictT, const float* __restrict__ dictnorm,
    const unsigned short* __restrict__ packB,
    float* __restrict__ out, double* __restrict__ block_sums)
{
    __shared__ __align__(16) unsigned short bstage[2][8 * 2048];  // 2 x 32 KB dbuf
    __shared__ float row_gap[RPB];
    __shared__ int   row_k1[RPB];
    __shared__ float red_d[256];
    __shared__ int   red_k[256];
    __shared__ float wred[4];
    __shared__ int   amb_list[RPB];
    __shared__ int   amb_cnt;

    const int tid  = threadIdx.x;
    const int ln   = tid & 63, wv = tid >> 6;
    const int l15  = ln & 15, q = ln >> 4;
    const int row0 = blockIdx.x * RPB;
    const int wrow = row0 + wv * 32;        // this wave's 32 rows

    // issue chunk-0 staging immediately; it flies while we convert A fragments
    STAGE(0, 0);
    if (tid == 0) amb_cnt = 0;

    // A fragments: 2 mtiles x 8 k-slices, register-resident for all 16 chunks.
    // lane provides A row m=l15 of mtile u (x row wrow + u*16 + l15), k = kk*32 + q*8 + j
    half8 afrag[2][8];
#pragma unroll
    for (int u = 0; u < 2; ++u) {
        const float* ar = x + (size_t)(wrow + u * 16 + l15) * DIM + q * 8;
#pragma unroll
        for (int kk = 0; kk < 8; ++kk) {
            const float4 p0 = *(const float4*)(ar + kk * 32);
            const float4 p1 = *(const float4*)(ar + kk * 32 + 4);
            half8 h;
            h[0] = (_Float16)p0.x; h[1] = (_Float16)p0.y; h[2] = (_Float16)p0.z; h[3] = (_Float16)p0.w;
            h[4] = (_Float16)p1.x; h[5] = (_Float16)p1.y; h[6] = (_Float16)p1.z; h[7] = (_Float16)p1.w;
            afrag[u][kk] = h;
        }
    }

    // packed top-2 per lane for its 8 C-rows (u in 2, i in 4): u32 = biased-dist bits | k
    unsigned p1v[2][4], p2v[2][4];
#pragma unroll
    for (int u = 0; u < 2; ++u)
#pragma unroll
        for (int i = 0; i < 4; ++i) { p1v[u][i] = 0xFFFFFFFFu; p2v[u][i] = 0xFFFFFFFFu; }

    __syncthreads();                         // chunk-0 staging complete

    for (int cc = 0; cc < 16; ++cc) {
        const int cur = cc & 1;
        if (cc < 15) STAGE(cur ^ 1, cc + 1);  // prefetch next chunk during compute

        const int c0 = cc * 64;
        float dn[4];
#pragma unroll
        for (int t = 0; t < 4; ++t) dn[t] = dictnorm[c0 + t * 16 + l15];   // ||d||^2 + 8

        const f32x4 zero = {0.f, 0.f, 0.f, 0.f};
        f32x4 acc[2][4];
#pragma unroll
        for (int u = 0; u < 2; ++u)
#pragma unroll
            for (int t = 0; t < 4; ++t) acc[u][t] = zero;

#pragma unroll
        for (int kk = 0; kk < 8; ++kk) {
#pragma unroll
            for (int t = 0; t < 4; ++t) {
                // lane-contiguous read: lane ln reads 16B at slot (t*64+ln) -> conflict-free
                const half8 b = *(const half8*)&bstage[cur][kk * 2048 + t * 512 + ln * 8];
                acc[0][t] = __builtin_amdgcn_mfma_f32_16x16x32_f16(afrag[0][kk], b, acc[0][t], 0, 0, 0);
                acc[1][t] = __builtin_amdgcn_mfma_f32_16x16x32_f16(afrag[1][kk], b, acc[1][t], 0, 0, 0);
            }
        }

        // packed top-2 update: 5 VALU/element, branchless, index-ascending tiebreak
#pragma unroll
        for (int t = 0; t < 4; ++t) {
            const unsigned kbase = (unsigned)(c0 + t * 16 + l15);
#pragma unroll
            for (int u = 0; u < 2; ++u)
#pragma unroll
                for (int i = 0; i < 4; ++i) {
                    const float s = fmaf(-2.f, acc[u][t][i], dn[t]);      // in (1.8, 14.6)
                    const unsigned pk = (__float_as_uint(s) & 0xFFFFFC00u) | kbase;
                    const unsigned mx = p1v[u][i] > pk ? p1v[u][i] : pk;  // max
                    p2v[u][i] = p2v[u][i] < mx ? p2v[u][i] : mx;          // min
                    p1v[u][i] = p1v[u][i] < pk ? p1v[u][i] : pk;          // min
                }
        }
        __syncthreads();    // staging for cc+1 complete; all waves done reading buf[cur]
    }

    // top-2 merge across the 16 lanes sharing quad q (same 8 output rows)
#pragma unroll
    for (int u = 0; u < 2; ++u)
#pragma unroll
        for (int i = 0; i < 4; ++i) {
            unsigned a1 = p1v[u][i], a2 = p2v[u][i];
#pragma unroll
            for (int m = 1; m < 16; m <<= 1) {
                const unsigned o1 = __shfl_xor(a1, m);
                const unsigned o2 = __shfl_xor(a2, m);
                const unsigned mx = a1 > o1 ? a1 : o1;
                a1 = a1 < o1 ? a1 : o1;
                const unsigned mn2 = a2 < o2 ? a2 : o2;
                a2 = mx < mn2 ? mx : mn2;
            }
            if (l15 == 0) {
                const int r = wv * 32 + u * 16 + q * 4 + i;
                row_k1[r]  = (int)(a1 & 1023u);
                row_gap[r] = __uint_as_float(a2 & 0xFFFFFC00u) - __uint_as_float(a1 & 0xFFFFFC00u);
            }
        }
    __syncthreads();

    if (tid < RPB && row_gap[tid] < EPS_TIE) {
        int p = atomicAdd(&amb_cnt, 1);
        amb_list[p] = tid;
    }
    __syncthreads();
    const int namb = amb_cnt;

    // np-fp32-faithful full rescan of ambiguous rows (proven; unchanged)
    for (int a = 0; a < namb; ++a) {
        const int r = amb_list[a];
        const float* xr = x + (size_t)(row0 + r) * DIM;
        const float nf = __fadd_rn(np_pairwise_sq_128(xr, 1), np_pairwise_sq_128(xr + 128, 1));
        float bd = 3.4e38f; int bk = 0x7fffffff;
#pragma unroll
        for (int i = 0; i < 4; ++i) {
            const int k = i * 256 + tid;                  // coalesced dict reads
            float sim = 0.f, nd = 0.f;
            for (int d = 0; d < DIM; ++d) {
                const float dv = dict[(size_t)d * NCODE + k];
                const float fv = xr[d];                    // broadcast (L1)
                sim = fmaf(fv, dv, sim);                   // BLAS-style FMA chain, d asc
                nd  = __fadd_rn(nd, __fmul_rn(dv, dv));    // np axis-0 reduce
            }
            const float dist = __fsub_rn(__fadd_rn(nf, nd), __fmul_rn(2.f, sim));
            if (dist < bd) { bd = dist; bk = k; }
        }
        red_d[tid] = bd; red_k[tid] = bk;
        __syncthreads();
        for (int s = 128; s > 0; s >>= 1) {
            if (tid < s) {
                const float od = red_d[tid + s]; const int ok = red_k[tid + s];
                if (od < red_d[tid] || (od == red_d[tid] && ok < red_k[tid])) {
                    red_d[tid] = od; red_k[tid] = ok;
                }
            }
            __syncthreads();
        }
        if (tid == 0) row_k1[r] = red_k[0];
        __syncthreads();
    }

    // epilogue: q = 0.5*dictT[kstar]; out = fl(x + fl(q-x)) (np-exact); loss partial
    float lsum = 0.f;
#pragma unroll 2
    for (int i = 0; i < 32; ++i) {
        const int e = i * 1024 + tid * 4;
        const int r = e >> 8, d0 = e & 255;
        const int kk = row_k1[r];
        const float4 dv = *(const float4*)&dictT[(size_t)kk * DIM + d0];
        const float4 xv = *(const float4*)&x[(size_t)row0 * DIM + e];
        float4 qv; qv.x = 0.5f * dv.x; qv.y = 0.5f * dv.y; qv.z = 0.5f * dv.z; qv.w = 0.5f * dv.w;
        float4 ov;
        ov.x = __fadd_rn(xv.x, __fsub_rn(qv.x, xv.x));
        ov.y = __fadd_rn(xv.y, __fsub_rn(qv.y, xv.y));
        ov.z = __fadd_rn(xv.z, __fsub_rn(qv.z, xv.z));
        ov.w = __fadd_rn(xv.w, __fsub_rn(qv.w, xv.w));
        const float e0 = __fsub_rn(xv.x, qv.x), e1 = __fsub_rn(xv.y, qv.y);
        const float e2 = __fsub_rn(xv.z, qv.z), e3 = __fsub_rn(xv.w, qv.w);
        lsum += e0 * e0 + e1 * e1 + e2 * e2 + e3 * e3;
        *(float4*)&out[(size_t)row0 * DIM + e] = ov;
    }

#pragma unroll
    for (int sft = 32; sft > 0; sft >>= 1) lsum += __shfl_down(lsum, sft, 64);
    if ((tid & 63) == 0) wred[tid >> 6] = lsum;
    __syncthreads();
    if (tid == 0)
        block_sums[blockIdx.x] = (double)((wred[0] + wred[1]) + (wred[2] + wred[3]));
}

// ---------- loss finalize ----------

__global__ void k_finalize(const double* __restrict__ block_sums, float* __restrict__ out_loss) {
    __shared__ double w[8];
    const int t = threadIdx.x;                  // 512 threads
    double v = block_sums[t];
#pragma unroll
    for (int sft = 32; sft > 0; sft >>= 1) v += __shfl_down(v, sft, 64);
    if ((t & 63) == 0) w[t >> 6] = v;
    __syncthreads();
    if (t == 0) {
        double tot = 0.0;
        for (int i = 0; i < 8; ++i) tot += w[i];
        out_loss[0] = (float)(1.25 * tot / (double)(NROWS * DIM));
    }
}

// ---------- launch ----------

extern "C" void kernel_launch(void* const* d_in, const int* in_sizes, int n_in,
                              void* d_out, int out_size, void* d_ws, size_t ws_size,
                              hipStream_t stream) {
    (void)in_sizes; (void)n_in; (void)out_size; (void)ws_size;
    const float* x    = (const float*)d_in[0];
    const float* dict = (const float*)d_in[1];
    float* out = (float*)d_out;

    char* ws = (char*)d_ws;
    float*          dictT      = (float*)ws;                          // 1 MB
    float*          dictnorm   = (float*)(ws + 1048576);              // 4 KB
    double*         block_sums = (double*)(ws + 1048576 + 4096);      // 8 KB (512 used)
    unsigned short* packB      = (unsigned short*)(ws + 1048576 + 4096 + 8192); // 512 KB

    k_prep<<<256, 256, 0, stream>>>(dict, dictT, dictnorm, packB);
    k_vq<<<NBLK, 256, 0, stream>>>(x, dict, dictT, dictnorm, packB, out, block_sums);
    k_finalize<<<1, NBLK, 0, stream>>>(block_sums, out + (size_t)NROWS * DIM);
}